// Round 6
// baseline (207.595 us; speedup 1.0000x reference)
//
#include <hip/hip_runtime.h>
#include <hip/hip_bf16.h>

#define BB 4
#define CC 128
#define TWOC 256
#define NN 4096
#define KK 16
#define COUT 256
#define BNK (BB*NN*KK)
#define NPB 16                    // nodes per k1 block (256 rows)
#define K1GRID (((BB*NN)/NPB)*2)  // 1024 M-tiles x 2 col-halves = 2048

typedef __attribute__((ext_vector_type(8))) short short8;
typedef __attribute__((ext_vector_type(4))) float f32x4;

__device__ __forceinline__ short f2bs(float f) {
  union { __hip_bfloat16 h; short s; } u;
  u.h = __float2bfloat16(f);
  return u.s;
}
__device__ __forceinline__ float bs2f(unsigned short s) {
  union { unsigned int u; float f; } v;
  v.u = ((unsigned int)s) << 16;
  return v.f;
}

// K0: transpose x [B][C][N] f32 -> featbf [B][N][C] bf16; convert w -> bf16; zero stats
__global__ void __launch_bounds__(256) k0_transpose(const float* __restrict__ x,
                                                    unsigned short* __restrict__ featbf,
                                                    const float* __restrict__ w,
                                                    unsigned short* __restrict__ wbf,
                                                    float* __restrict__ gsum,
                                                    float* __restrict__ gsq) {
  __shared__ float tile[64][129];
  int b = blockIdx.x >> 6;
  int n0 = (blockIdx.x & 63) << 6;
  int t = threadIdx.x;
  if (blockIdx.x == 0) { gsum[t] = 0.f; gsq[t] = 0.f; }
  // w is 65536 elems; 256 blocks x 256 thr -> 1 elem each
  wbf[blockIdx.x * 256 + t] = (unsigned short)f2bs(w[blockIdx.x * 256 + t]);
#pragma unroll
  for (int i = 0; i < 32; ++i) {
    int flat = t + i * 256;
    int c = flat >> 6;
    int nl = flat & 63;
    tile[nl][c] = x[((size_t)(b * CC + c) * NN) + n0 + nl];
  }
  __syncthreads();
#pragma unroll
  for (int i = 0; i < 8; ++i) {
    int e = t + i * 256;
    int c4 = (e & 31) << 2;
    int nl = e >> 5;
    ushort4 u;
    u.x = (unsigned short)f2bs(tile[nl][c4 + 0]);
    u.y = (unsigned short)f2bs(tile[nl][c4 + 1]);
    u.z = (unsigned short)f2bs(tile[nl][c4 + 2]);
    u.w = (unsigned short)f2bs(tile[nl][c4 + 3]);
    *(ushort4*)(featbf + ((size_t)(b * NN + n0 + nl) * CC + c4)) = u;
  }
}

// K1: 256-row (16-node) x 128-col GEMM tile per block; W in LDS; 2 K-steps.
// 512 thr = 8 waves (4 row-waves x 2 col-waves), each wave 64x64 out.
__global__ void __launch_bounds__(512, 1) k1_main(
    const unsigned short* __restrict__ featbf,
    const unsigned short* __restrict__ wbf,
    const float* __restrict__ bias,
    const int* __restrict__ eidx,
    unsigned short* __restrict__ nmaxh, unsigned short* __restrict__ nminh,
    float* __restrict__ gsum, float* __restrict__ gsq)
{
  extern __shared__ char lds[];
  char* sB = lds;            // 128 cols x 512 B = 64 KB  ([col][k0..255] bf16, swizzled)
  char* sA = lds + 65536;    // 256 rows x 256 B = 64 KB  (per-step k-half, swizzled)

  const int tid  = threadIdx.x;
  const int lane = tid & 63;
  const int wv   = tid >> 6;
  const int l15  = lane & 15;
  const int lhi  = lane >> 4;
  const int wr   = wv >> 1;        // 0..3 row-wave
  const int wc   = wv & 1;         // 0..1 col-wave

  const int mt  = (int)blockIdx.x >> 1;
  const int chf = (int)blockIdx.x & 1;   // which 128-col half
  const int g0  = mt * NPB;
  const int b   = g0 >> 12;
  const int n0  = g0 & (NN - 1);
  const unsigned short* fb = featbf + (size_t)b * NN * CC;

  // ---------- stage B (once): cols chf*128 .. +128, all 256 k ----------
  {
    const int col = tid >> 2;            // 0..127
    const int kb  = (tid & 3) * 64;      // elem base 0/64/128/192
    const unsigned short* src = wbf + (size_t)(chf * 128 + col) * TWOC + kb;
    const int ab = col * 512 + kb * 2;
    const int sw = (col & 7) << 4;
#pragma unroll
    for (int j = 0; j < 8; ++j)
      *(uint4*)(sB + ((ab + j * 16) ^ sw)) = *(const uint4*)((const char*)src + j * 16);
  }

  // ---------- A staging assignment: row = (tid>>4) + 32p, 16B chunk = tid&15 ----------
  const int r0 = tid >> 4;   // 0..31
  const int ch = tid & 15;   // chunk id; elem offset ch*8, byte offset ch*16
  int idxi[8], idxj[8];
#pragma unroll
  for (int p = 0; p < 8; ++p) {
    int row = r0 + 32 * p;
    int ebase = (b * NN + n0 + (row >> 4)) * KK + (row & 15);
    idxj[p] = eidx[ebase];          // edge_index[0] -> x_j
    idxi[p] = eidx[BNK + ebase];    // edge_index[1] -> x_i
  }
  uint4 fi[8];
#pragma unroll
  for (int p = 0; p < 8; ++p)
    fi[p] = *(const uint4*)(fb + (size_t)idxi[p] * CC + ch * 8);
  // write A-step0 = x_i rows
#pragma unroll
  for (int p = 0; p < 8; ++p) {
    int row = r0 + 32 * p;
    *(uint4*)(sA + ((row * 256 + ch * 16) ^ ((row & 7) << 4))) = fi[p];
  }
  // issue x_j gathers now; consumed after MFMA step 0 (latency hidden)
  uint4 fj[8];
#pragma unroll
  for (int p = 0; p < 8; ++p)
    fj[p] = *(const uint4*)(fb + (size_t)idxj[p] * CC + ch * 8);

  __syncthreads();

  f32x4 acc[4][4] = {};
  const int asw = (l15 & 7) << 4;

  // ---------- MFMA step 0 (k = 0..127) ----------
#pragma unroll
  for (int kk = 0; kk < 4; ++kk) {
    short8 a[4], bg[4];
#pragma unroll
    for (int rt = 0; rt < 4; ++rt) {
      int row = wr * 64 + rt * 16 + l15;
      a[rt] = *(short8*)(sA + ((row * 256 + kk * 64 + lhi * 16) ^ asw));
    }
#pragma unroll
    for (int ct = 0; ct < 4; ++ct) {
      int col = wc * 64 + ct * 16 + l15;
      bg[ct] = *(short8*)(sB + ((col * 512 + kk * 64 + lhi * 16) ^ asw));
    }
#pragma unroll
    for (int rt = 0; rt < 4; ++rt)
#pragma unroll
      for (int ct = 0; ct < 4; ++ct)
        acc[rt][ct] = __builtin_amdgcn_mfma_f32_16x16x32_bf16(a[rt], bg[ct], acc[rt][ct], 0, 0, 0);
  }
  __syncthreads();   // all A0 reads complete before overwrite

  // ---------- stage A-step1 = x_j - x_i ----------
#pragma unroll
  for (int p = 0; p < 8; ++p) {
    uint4 d;
    unsigned int* pi = (unsigned int*)&fi[p];
    unsigned int* pj = (unsigned int*)&fj[p];
    unsigned int* pd = (unsigned int*)&d;
#pragma unroll
    for (int q = 0; q < 4; ++q) {
      float lo = bs2f((unsigned short)(pj[q] & 0xffff)) - bs2f((unsigned short)(pi[q] & 0xffff));
      float hi = bs2f((unsigned short)(pj[q] >> 16))    - bs2f((unsigned short)(pi[q] >> 16));
      pd[q] = ((unsigned int)(unsigned short)f2bs(lo)) |
              (((unsigned int)(unsigned short)f2bs(hi)) << 16);
    }
    int row = r0 + 32 * p;
    *(uint4*)(sA + ((row * 256 + ch * 16) ^ ((row & 7) << 4))) = d;
  }
  __syncthreads();

  // ---------- MFMA step 1 (k = 128..255 -> sB byte offset +256) ----------
#pragma unroll
  for (int kk = 0; kk < 4; ++kk) {
    short8 a[4], bg[4];
#pragma unroll
    for (int rt = 0; rt < 4; ++rt) {
      int row = wr * 64 + rt * 16 + l15;
      a[rt] = *(short8*)(sA + ((row * 256 + kk * 64 + lhi * 16) ^ asw));
    }
#pragma unroll
    for (int ct = 0; ct < 4; ++ct) {
      int col = wc * 64 + ct * 16 + l15;
      bg[ct] = *(short8*)(sB + ((col * 512 + 256 + kk * 64 + lhi * 16) ^ asw));
    }
#pragma unroll
    for (int rt = 0; rt < 4; ++rt)
#pragma unroll
      for (int ct = 0; ct < 4; ++ct)
        acc[rt][ct] = __builtin_amdgcn_mfma_f32_16x16x32_bf16(a[rt], bg[ct], acc[rt][ct], 0, 0, 0);
  }

  // ---------- epilogue: relu, per-node K-max/min, stats ----------
  float biasv[4];
#pragma unroll
  for (int ct = 0; ct < 4; ++ct) biasv[ct] = bias[chf * 128 + wc * 64 + ct * 16 + l15];

  float cs[4] = {0.f, 0.f, 0.f, 0.f};
  float cq[4] = {0.f, 0.f, 0.f, 0.f};
#pragma unroll
  for (int rt = 0; rt < 4; ++rt) {
    const int g = g0 + wr * 4 + rt;   // one node per 16-row tile
#pragma unroll
    for (int ct = 0; ct < 4; ++ct) {
      float vmax = -1e30f, vmin = 1e30f;
#pragma unroll
      for (int i = 0; i < 4; ++i) {
        float v = fmaxf(acc[rt][ct][i] + biasv[ct], 0.f);
        vmax = fmaxf(vmax, v);
        vmin = fminf(vmin, v);
        cs[ct] += v;
        cq[ct] += v * v;
      }
      vmax = fmaxf(vmax, __shfl_xor(vmax, 16));
      vmax = fmaxf(vmax, __shfl_xor(vmax, 32));
      vmin = fminf(vmin, __shfl_xor(vmin, 16));
      vmin = fminf(vmin, __shfl_xor(vmin, 32));
      if (lane < 16) {
        int col = chf * 128 + wc * 64 + ct * 16 + l15;
        nmaxh[(size_t)g * COUT + col] = (unsigned short)f2bs(vmax);
        nminh[(size_t)g * COUT + col] = (unsigned short)f2bs(vmin);
      }
    }
  }
#pragma unroll
  for (int ct = 0; ct < 4; ++ct) {
    float s = cs[ct], q = cq[ct];
    s += __shfl_xor(s, 16);  s += __shfl_xor(s, 32);
    q += __shfl_xor(q, 16);  q += __shfl_xor(q, 32);
    if (lane < 16) {
      int col = chf * 128 + wc * 64 + ct * 16 + l15;
      atomicAdd(&gsum[col], s);
      atomicAdd(&gsq[col], q);
    }
  }
}

// K2: BN-affine finalize + monotone max/min select (bf16 in) + transposed out
__global__ void __launch_bounds__(256) k2_out(const unsigned short* __restrict__ nmaxh,
                                              const unsigned short* __restrict__ nminh,
                                              const float* __restrict__ gsum,
                                              const float* __restrict__ gsq,
                                              const float* __restrict__ gamma,
                                              const float* __restrict__ beta,
                                              float* __restrict__ out) {
  __shared__ float tile[COUT][33];
  int b = blockIdx.x >> 7;
  int n0 = (blockIdx.x & 127) << 5;
  int t = threadIdx.x;
  const float inv = 1.0f / (float)BNK;
  float mean = gsum[t] * inv;
  float var  = gsq[t] * inv - mean * mean;
  float sc = gamma[t] * rsqrtf(var + 1e-5f);
  float sh = beta[t] - mean * sc;
  const unsigned short* src = (sc >= 0.f) ? nmaxh : nminh;
#pragma unroll
  for (int rr = 0; rr < 32; ++rr) {
    size_t g = (size_t)(b * NN + n0 + rr) * COUT + t;
    tile[t][rr] = bs2f(src[g]) * sc + sh;
  }
  __syncthreads();
#pragma unroll
  for (int i = 0; i < 32; ++i) {
    int o = i * 8 + (t >> 5);
    int nl = t & 31;
    out[((size_t)(b * COUT + o) * NN) + n0 + nl] = tile[o][nl];
  }
}

extern "C" void kernel_launch(void* const* d_in, const int* in_sizes, int n_in,
                              void* d_out, int out_size, void* d_ws, size_t ws_size,
                              hipStream_t stream) {
  const float* x     = (const float*)d_in[0];
  const float* w     = (const float*)d_in[1];
  const float* bias  = (const float*)d_in[2];
  const float* gamma = (const float*)d_in[3];
  const float* beta  = (const float*)d_in[4];
  const int*   eidx  = (const int*)d_in[5];

  char* ws = (char*)d_ws;
  unsigned short* featbf = (unsigned short*)(ws);              //  4,194,304 B
  unsigned short* wbf    = (unsigned short*)(ws + 4194304);    //    131,072 B
  unsigned short* nmaxh  = (unsigned short*)(ws + 4325376);    //  8,388,608 B
  unsigned short* nminh  = (unsigned short*)(ws + 12713984);   //  8,388,608 B
  float* gsum = (float*)(ws + 21102592);                       //      1,024 B
  float* gsq  = (float*)(ws + 21103616);                       //      1,024 B
  float* out = (float*)d_out;

  k0_transpose<<<256, 256, 0, stream>>>(x, featbf, w, wbf, gsum, gsq);
  k1_main<<<K1GRID, 512, 131072, stream>>>(featbf, wbf, bias, eidx, nmaxh, nminh, gsum, gsq);
  k2_out<<<512, 256, 0, stream>>>(nmaxh, nminh, gsum, gsq, gamma, beta, out);
}

// Round 7
// 206.570 us; speedup vs baseline: 1.0050x; 1.0050x over previous
//
#include <hip/hip_runtime.h>
#include <hip/hip_bf16.h>

#define BB 4
#define CC 128
#define TWOC 256
#define NN 4096
#define KK 16
#define COUT 256
#define BNK (BB*NN*KK)      // 262144
#define NODES (BB*NN)       // 16384
#define NPB 64              // nodes per k1 block
#define NGRP (NPB/4)        // 16 groups of 4 nodes
#define NIT (NGRP*4)        // 64 pipelined iterations per wave
#define K1GRID (NODES/NPB)  // 256

typedef __attribute__((ext_vector_type(8))) short short8;
typedef __attribute__((ext_vector_type(4))) float f32x4;

static __device__ __forceinline__ short f2bs(float f) {
  union { __hip_bfloat16 h; short s; } u;
  u.h = __float2bfloat16(f);
  return u.s;
}
static __device__ __forceinline__ float bs2f(unsigned short s) {
  union { unsigned int u; float f; } v;
  v.u = ((unsigned int)s) << 16;
  return v.f;
}

// K0: transpose x [B][C][N] f32 -> featbf [B][N][C] bf16;
//     W split: w1 = W_left - W_right, w2 = W_right, both [256 col][128 k] bf16; zero stats.
__global__ void __launch_bounds__(256) k0_prep(const float* __restrict__ x,
                                               unsigned short* __restrict__ featbf,
                                               const float* __restrict__ w,
                                               unsigned short* __restrict__ w1c,
                                               unsigned short* __restrict__ w2c,
                                               float* __restrict__ gsum,
                                               float* __restrict__ gsq) {
  __shared__ float tile[64][129];
  int b = blockIdx.x >> 6;
  int n0 = (blockIdx.x & 63) << 6;
  int t = threadIdx.x;
  if (blockIdx.x == 0) { gsum[t] = 0.f; gsq[t] = 0.f; }
  {
    int col = blockIdx.x;          // 256 blocks = 256 cols
    if (t < CC) {
      float wl = w[col * TWOC + t];
      float wr = w[col * TWOC + CC + t];
      w1c[col * CC + t] = (unsigned short)f2bs(wl - wr);
      w2c[col * CC + t] = (unsigned short)f2bs(wr);
    }
  }
#pragma unroll
  for (int i = 0; i < 32; ++i) {
    int flat = t + i * 256;
    int c = flat >> 6;
    int nl = flat & 63;
    tile[nl][c] = x[((size_t)(b * CC + c) * NN) + n0 + nl];
  }
  __syncthreads();
#pragma unroll
  for (int i = 0; i < 8; ++i) {
    int e = t + i * 256;
    int c4 = (e & 31) << 2;
    int nl = e >> 5;
    ushort4 u;
    u.x = (unsigned short)f2bs(tile[nl][c4 + 0]);
    u.y = (unsigned short)f2bs(tile[nl][c4 + 1]);
    u.z = (unsigned short)f2bs(tile[nl][c4 + 2]);
    u.w = (unsigned short)f2bs(tile[nl][c4 + 3]);
    *(ushort4*)(featbf + ((size_t)(b * NN + n0 + nl) * CC + c4)) = u;
  }
}

// K1: LDS-free gather-GEMM. 8 independent waves x 32 cols; per wave: groups of
// 4 nodes (4 row-tiles of 4nodes x 4k); A-frags gathered straight from featbf
// (16B/lane); W1/W2 fragments register-resident; y = W1*x_i + W2*x_j;
// K-max/min fully in-lane (lane lhi owns node lhi); double-buffered prefetch.
__global__ void __launch_bounds__(512, 2) k1_main(
    const unsigned short* __restrict__ featbf,
    const unsigned short* __restrict__ w1c,
    const unsigned short* __restrict__ w2c,
    const float* __restrict__ bias,
    const int* __restrict__ eidx,
    unsigned short* __restrict__ nmaxh, unsigned short* __restrict__ nminh,
    float* __restrict__ gsum, float* __restrict__ gsq)
{
  const int tid  = threadIdx.x;
  const int wv   = tid >> 6;
  const int lane = tid & 63;
  const int l15  = lane & 15;
  const int lhi  = lane >> 4;
  const int colbase = wv * 32;

  const int g0 = blockIdx.x * NPB;
  const int b  = g0 >> 12;
  const unsigned short* fbb = featbf + ((size_t)b * NN) * CC;

  // W fragments: B[k][col] = Wx[col][k]; lane: col = colbase+ct*16+l15, k = t*32+lhi*8
  short8 w1f[4][2], w2f[4][2];
#pragma unroll
  for (int t = 0; t < 4; ++t)
#pragma unroll
    for (int ct = 0; ct < 2; ++ct) {
      int col = colbase + ct * 16 + l15;
      w1f[t][ct] = *(const short8*)(w1c + (size_t)col * CC + t * 32 + lhi * 8);
      w2f[t][ct] = *(const short8*)(w2c + (size_t)col * CC + t * 32 + lhi * 8);
    }
  float biasv[2] = { bias[colbase + l15], bias[colbase + 16 + l15] };

  float cs[2] = {0.f, 0.f};
  float cq[2] = {0.f, 0.f};
  float vmax[2], vmin[2];

  // per-lane row geometry: A-tile row = l15 = (node_local=l15>>2)*4 + (kq=l15&3)
  const int nl4 = l15 >> 2;
  const int kq  = l15 & 3;
  const int* e0 = eidx + ((size_t)g0 * KK + nl4 * KK + kq);  // x_j indices
  const int* e1 = e0 + BNK;                                   // x_i indices
  // iter q: group=q>>2, rt=q&3; edge offset = (q>>2)*64 + (q&3)*4
  auto qoff = [&](int q) { return ((q >> 2) << 6) + ((q & 3) << 2); };

  int ejA, eiA, ejB, eiB;
  short8 xiA[4], xjA[4], xiB[4], xjB[4];

  ejA = e0[qoff(0)]; eiA = e1[qoff(0)];
  ejB = e0[qoff(1)]; eiB = e1[qoff(1)];
#pragma unroll
  for (int t = 0; t < 4; ++t) {
    xiA[t] = *(const short8*)(fbb + (size_t)eiA * CC + t * 32 + lhi * 8);
    xjA[t] = *(const short8*)(fbb + (size_t)ejA * CC + t * 32 + lhi * 8);
  }

  auto body = [&](int RT, int q,
                  int& ejC, int& eiC, short8 (&xiC)[4], short8 (&xjC)[4],
                  int ejN, int eiN, short8 (&xiN)[4], short8 (&xjN)[4]) {
    // prefetch idx for q+2 into the current (just-consumed) idx regs
    if (q + 2 < NIT) {
      int o = qoff(q + 2);
      ejC = e0[o];
      eiC = e1[o];
    }
    // prefetch frags for q+1 into the other buffer
    if (q + 1 < NIT) {
#pragma unroll
      for (int t = 0; t < 4; ++t) {
        xiN[t] = *(const short8*)(fbb + (size_t)eiN * CC + t * 32 + lhi * 8);
        xjN[t] = *(const short8*)(fbb + (size_t)ejN * CC + t * 32 + lhi * 8);
      }
    }
    // 16 MFMAs on current frags
    f32x4 acc[2] = {};
#pragma unroll
    for (int t = 0; t < 4; ++t) {
      acc[0] = __builtin_amdgcn_mfma_f32_16x16x32_bf16(xiC[t], w1f[t][0], acc[0], 0, 0, 0);
      acc[1] = __builtin_amdgcn_mfma_f32_16x16x32_bf16(xiC[t], w1f[t][1], acc[1], 0, 0, 0);
    }
#pragma unroll
    for (int t = 0; t < 4; ++t) {
      acc[0] = __builtin_amdgcn_mfma_f32_16x16x32_bf16(xjC[t], w2f[t][0], acc[0], 0, 0, 0);
      acc[1] = __builtin_amdgcn_mfma_f32_16x16x32_bf16(xjC[t], w2f[t][1], acc[1], 0, 0, 0);
    }
    // epilogue: D row = lhi*4+i -> node lhi, k = RT*4+i. All in-lane.
    if (RT == 0) { vmax[0] = 0.f; vmax[1] = 0.f; vmin[0] = 1e30f; vmin[1] = 1e30f; }
#pragma unroll
    for (int ct = 0; ct < 2; ++ct) {
#pragma unroll
      for (int i = 0; i < 4; ++i) {
        float v = fmaxf(acc[ct][i] + biasv[ct], 0.f);
        vmax[ct] = fmaxf(vmax[ct], v);
        vmin[ct] = fminf(vmin[ct], v);
        cs[ct] += v;
        cq[ct] += v * v;
      }
    }
    if (RT == 3) {
      int g = g0 + ((q >> 2) << 2) + lhi;   // node owned by this lane
#pragma unroll
      for (int ct = 0; ct < 2; ++ct) {
        size_t o = (size_t)g * COUT + colbase + ct * 16 + l15;
        nmaxh[o] = (unsigned short)f2bs(vmax[ct]);
        nminh[o] = (unsigned short)f2bs(vmin[ct]);
      }
    }
  };

  for (int grp = 0; grp < NGRP; ++grp) {
    int q = grp << 2;
    body(0, q,     ejA, eiA, xiA, xjA, ejB, eiB, xiB, xjB);
    body(1, q + 1, ejB, eiB, xiB, xjB, ejA, eiA, xiA, xjA);
    body(2, q + 2, ejA, eiA, xiA, xjA, ejB, eiB, xiB, xjB);
    body(3, q + 3, ejB, eiB, xiB, xjB, ejA, eiA, xiA, xjA);
  }

  // stats: sum over lhi (4 nodes' partials share the same col), one atomic per col
#pragma unroll
  for (int ct = 0; ct < 2; ++ct) {
    float s = cs[ct];
    s += __shfl_xor(s, 16); s += __shfl_xor(s, 32);
    float qq = cq[ct];
    qq += __shfl_xor(qq, 16); qq += __shfl_xor(qq, 32);
    if (lane < 16) {
      atomicAdd(&gsum[colbase + ct * 16 + l15], s);
      atomicAdd(&gsq[colbase + ct * 16 + l15], qq);
    }
  }
}

// K2: BN-affine finalize + monotone max/min select (bf16 in) + transposed output
__global__ void __launch_bounds__(256) k2_out(const unsigned short* __restrict__ nmaxh,
                                              const unsigned short* __restrict__ nminh,
                                              const float* __restrict__ gsum,
                                              const float* __restrict__ gsq,
                                              const float* __restrict__ gamma,
                                              const float* __restrict__ beta,
                                              float* __restrict__ out) {
  __shared__ float tile[COUT][33];
  int b = blockIdx.x >> 7;
  int n0 = (blockIdx.x & 127) << 5;
  int t = threadIdx.x;
  const float inv = 1.0f / (float)BNK;
  float mean = gsum[t] * inv;
  float var  = gsq[t] * inv - mean * mean;
  float sc = gamma[t] * rsqrtf(var + 1e-5f);
  float sh = beta[t] - mean * sc;
  const unsigned short* src = (sc >= 0.f) ? nmaxh : nminh;
#pragma unroll
  for (int rr = 0; rr < 32; ++rr) {
    size_t g = (size_t)(b * NN + n0 + rr) * COUT + t;
    tile[t][rr] = bs2f(src[g]) * sc + sh;
  }
  __syncthreads();
#pragma unroll
  for (int i = 0; i < 32; ++i) {
    int o = i * 8 + (t >> 5);
    int nl = t & 31;
    out[((size_t)(b * COUT + o) * NN) + n0 + nl] = tile[o][nl];
  }
}

extern "C" void kernel_launch(void* const* d_in, const int* in_sizes, int n_in,
                              void* d_out, int out_size, void* d_ws, size_t ws_size,
                              hipStream_t stream) {
  const float* x     = (const float*)d_in[0];
  const float* w     = (const float*)d_in[1];
  const float* bias  = (const float*)d_in[2];
  const float* gamma = (const float*)d_in[3];
  const float* beta  = (const float*)d_in[4];
  const int*   eidx  = (const int*)d_in[5];

  char* ws = (char*)d_ws;
  unsigned short* featbf = (unsigned short*)(ws);              //  4,194,304 B
  unsigned short* w1c    = (unsigned short*)(ws + 4194304);    //     65,536 B
  unsigned short* w2c    = (unsigned short*)(ws + 4259840);    //     65,536 B
  unsigned short* nmaxh  = (unsigned short*)(ws + 4325376);    //  8,388,608 B
  unsigned short* nminh  = (unsigned short*)(ws + 12713984);   //  8,388,608 B
  float* gsum = (float*)(ws + 21102592);                       //      1,024 B
  float* gsq  = (float*)(ws + 21103616);                       //      1,024 B
  float* out = (float*)d_out;

  k0_prep<<<256, 256, 0, stream>>>(x, featbf, w, w1c, w2c, gsum, gsq);
  k1_main<<<K1GRID, 512, 0, stream>>>(featbf, w1c, w2c, bias, eidx, nmaxh, nminh, gsum, gsq);
  k2_out<<<512, 256, 0, stream>>>(nmaxh, nminh, gsum, gsq, gamma, beta, out);
}

// Round 10
// 139.640 us; speedup vs baseline: 1.4866x; 1.4793x over previous
//
#include <hip/hip_runtime.h>
#include <hip/hip_bf16.h>

#define BB 4
#define CC 128
#define TWOC 256
#define NN 4096
#define KK 16
#define COUT 256
#define BNK (BB*NN*KK)      // 262144
#define NODES (BB*NN)       // 16384

typedef __attribute__((ext_vector_type(8))) short short8;
typedef __attribute__((ext_vector_type(4))) float f32x4;

static __device__ __forceinline__ unsigned short f2bs(float f) {
  union { __hip_bfloat16 h; unsigned short s; } u;
  u.h = __float2bfloat16(f);
  return u.s;
}
static __device__ __forceinline__ float bs2f(unsigned short s) {
  union { unsigned int u; float f; } v;
  v.u = ((unsigned int)s) << 16;
  return v.f;
}

// K0: transpose x [B][C][N] f32 -> featbf [B*N][128] bf16;
//     pack W12 [512 col][128 k] bf16: col<256 -> W_L - W_R, col>=256 -> W_R; zero stats.
__global__ void __launch_bounds__(256) k0_prep(const float* __restrict__ x,
                                               unsigned short* __restrict__ featbf,
                                               const float* __restrict__ w,
                                               unsigned short* __restrict__ w12,
                                               float* __restrict__ gsum,
                                               float* __restrict__ gsq) {
  __shared__ float tile[64][129];
  int b = blockIdx.x >> 6;
  int n0 = (blockIdx.x & 63) << 6;
  int t = threadIdx.x;
  if (blockIdx.x == 0) { gsum[t] = 0.f; gsq[t] = 0.f; }
  {
    int flat = blockIdx.x * 256 + t;      // 0..65535 over [512][128]
    int col = flat >> 7, k = flat & 127;
    float v = (col < COUT) ? (w[col * TWOC + k] - w[col * TWOC + CC + k])
                           : w[(col - COUT) * TWOC + CC + k];
    w12[flat] = f2bs(v);
  }
#pragma unroll
  for (int i = 0; i < 32; ++i) {
    int flat = t + i * 256;
    int c = flat >> 6;
    int nl = flat & 63;
    tile[nl][c] = x[((size_t)(b * CC + c) * NN) + n0 + nl];
  }
  __syncthreads();
#pragma unroll
  for (int i = 0; i < 8; ++i) {
    int e = t + i * 256;
    int c4 = (e & 31) << 2;
    int nl = e >> 5;
    ushort4 u;
    u.x = f2bs(tile[nl][c4 + 0]);
    u.y = f2bs(tile[nl][c4 + 1]);
    u.z = f2bs(tile[nl][c4 + 2]);
    u.w = f2bs(tile[nl][c4 + 3]);
    *(ushort4*)(featbf + ((size_t)(b * NN + n0 + nl) * CC + c4)) = u;
  }
}

// K1: dense streaming GEMM Y[16384][512] = feat[16384][128] @ W12^T. No LDS, no
// gathers. 4 waves/block, each wave 32 cols x 64 rows (4 iters of 16 rows),
// W-frags register-resident (32 VGPR), A double-buffered. Batch->XCD pinned.
__global__ void __launch_bounds__(256, 4) k1_gemm(
    const unsigned short* __restrict__ featbf,
    const unsigned short* __restrict__ w12,
    unsigned short* __restrict__ Y)
{
  const int tid = threadIdx.x;
  const int wv   = tid >> 6;
  const int lane = tid & 63;
  const int l15  = lane & 15;
  const int lhi  = lane >> 4;
  const int bid  = blockIdx.x;
  // batch pinned to XCD pair: xcd = bid&7 -> b = xcd>>1
  const int b = (bid & 7) >> 1;
  const int inner = ((bid >> 3) << 1) | (bid & 1);   // 0..255 within batch
  const int rb = inner >> 2;                          // 0..63 rowblock (64 rows)
  const int cg = (inner & 3) * 4 + wv;                // 0..15 colgroup
  const int colbase = cg * 32;
  const int row0 = b * NN + rb * 64;

  short8 wf[4][2];
#pragma unroll
  for (int t = 0; t < 4; ++t)
#pragma unroll
    for (int ct = 0; ct < 2; ++ct)
      wf[t][ct] = *(const short8*)(w12 + (size_t)(colbase + ct * 16 + l15) * CC + t * 32 + lhi * 8);

  short8 aA[4], aB[4];
#pragma unroll
  for (int t = 0; t < 4; ++t)
    aA[t] = *(const short8*)(featbf + (size_t)(row0 + l15) * CC + t * 32 + lhi * 8);

#pragma unroll
  for (int it = 0; it < 4; ++it) {
    short8* cur = (it & 1) ? aB : aA;
    short8* nxt = (it & 1) ? aA : aB;
    if (it < 3) {
      int r = row0 + (it + 1) * 16 + l15;
#pragma unroll
      for (int t = 0; t < 4; ++t)
        nxt[t] = *(const short8*)(featbf + (size_t)r * CC + t * 32 + lhi * 8);
    }
    f32x4 acc0 = {}, acc1 = {};
#pragma unroll
    for (int t = 0; t < 4; ++t) {
      acc0 = __builtin_amdgcn_mfma_f32_16x16x32_bf16(cur[t], wf[t][0], acc0, 0, 0, 0);
      acc1 = __builtin_amdgcn_mfma_f32_16x16x32_bf16(cur[t], wf[t][1], acc1, 0, 0, 0);
    }
    const int orow0 = row0 + it * 16;
#pragma unroll
    for (int i = 0; i < 4; ++i) {
      unsigned short* yr = Y + (size_t)(orow0 + lhi * 4 + i) * 512 + colbase + l15;
      yr[0]  = f2bs(acc0[i]);
      yr[16] = f2bs(acc1[i]);
    }
  }
}

// K2: edge phase. Per wave: 4 nodes; per edge read Y[i][c] (U) + Y[j][256+c] (V),
// y = U+V+bias, relu; in-lane minmax over 16 edges (lane owns 4 cols); stats
// pre-reduced in LDS -> 2 atomics/col/block. Batch->XCD pinned for Y L2 locality.
__global__ void __launch_bounds__(256, 4) k2_edge(
    const unsigned short* __restrict__ Y,
    const float* __restrict__ bias,
    const int* __restrict__ eidx,
    unsigned short* __restrict__ nmaxh, unsigned short* __restrict__ nminh,
    float* __restrict__ gsum, float* __restrict__ gsq)
{
  __shared__ float sred[2][4][256];
  const int tid = threadIdx.x;
  const int wv   = tid >> 6;
  const int lane = tid & 63;
  const int bid  = blockIdx.x;
  const int b = (bid & 7) >> 1;
  const int inner = ((bid >> 3) << 1) | (bid & 1);   // 0..255
  const int nbase = b * NN + inner * 16 + wv * 4;    // 4 nodes per wave
  const int c0 = lane * 4;

  const float bv0 = bias[c0], bv1 = bias[c0 + 1], bv2 = bias[c0 + 2], bv3 = bias[c0 + 3];
  const unsigned short* Yb = Y + (size_t)b * NN * 512;

  float ssum[4] = {0.f, 0.f, 0.f, 0.f};
  float ssq[4]  = {0.f, 0.f, 0.f, 0.f};

#pragma unroll
  for (int nn = 0; nn < 4; ++nn) {
    const int node = nbase + nn;
    const int* ej = eidx + (size_t)node * KK;
    const int* ei = ej + BNK;
    int4 ej4[4], ei4[4];
#pragma unroll
    for (int u = 0; u < 4; ++u) {
      ej4[u] = *(const int4*)(ej + u * 4);
      ei4[u] = *(const int4*)(ei + u * 4);
    }
    float mx[4] = {0.f, 0.f, 0.f, 0.f};
    float mn[4] = {1e30f, 1e30f, 1e30f, 1e30f};
#pragma unroll
    for (int e = 0; e < 16; ++e) {
      const int jj = ((const int*)ej4)[e];
      const int ii = ((const int*)ei4)[e];
      ushort4 uu = *(const ushort4*)(Yb + (size_t)ii * 512 + c0);
      ushort4 vv = *(const ushort4*)(Yb + (size_t)jj * 512 + 256 + c0);
      float y0 = fmaxf(bs2f(uu.x) + bs2f(vv.x) + bv0, 0.f);
      float y1 = fmaxf(bs2f(uu.y) + bs2f(vv.y) + bv1, 0.f);
      float y2 = fmaxf(bs2f(uu.z) + bs2f(vv.z) + bv2, 0.f);
      float y3 = fmaxf(bs2f(uu.w) + bs2f(vv.w) + bv3, 0.f);
      mx[0] = fmaxf(mx[0], y0); mn[0] = fminf(mn[0], y0); ssum[0] += y0; ssq[0] += y0 * y0;
      mx[1] = fmaxf(mx[1], y1); mn[1] = fminf(mn[1], y1); ssum[1] += y1; ssq[1] += y1 * y1;
      mx[2] = fmaxf(mx[2], y2); mn[2] = fminf(mn[2], y2); ssum[2] += y2; ssq[2] += y2 * y2;
      mx[3] = fmaxf(mx[3], y3); mn[3] = fminf(mn[3], y3); ssum[3] += y3; ssq[3] += y3 * y3;
    }
    ushort4 om, on;
    om.x = f2bs(mx[0]); om.y = f2bs(mx[1]); om.z = f2bs(mx[2]); om.w = f2bs(mx[3]);
    on.x = f2bs(mn[0]); on.y = f2bs(mn[1]); on.z = f2bs(mn[2]); on.w = f2bs(mn[3]);
    *(ushort4*)(nmaxh + (size_t)node * COUT + c0) = om;
    *(ushort4*)(nminh + (size_t)node * COUT + c0) = on;
  }

#pragma unroll
  for (int m = 0; m < 4; ++m) {
    sred[0][wv][c0 + m] = ssum[m];
    sred[1][wv][c0 + m] = ssq[m];
  }
  __syncthreads();
  {
    const int c = tid;   // 0..255
    float s = sred[0][0][c] + sred[0][1][c] + sred[0][2][c] + sred[0][3][c];
    float q = sred[1][0][c] + sred[1][1][c] + sred[1][2][c] + sred[1][3][c];
    atomicAdd(&gsum[c], s);
    atomicAdd(&gsq[c], q);
  }
}

// K3: BN-affine finalize + monotone max/min select (bf16 in) + transposed output
__global__ void __launch_bounds__(256) k3_out(const unsigned short* __restrict__ nmaxh,
                                              const unsigned short* __restrict__ nminh,
                                              const float* __restrict__ gsum,
                                              const float* __restrict__ gsq,
                                              const float* __restrict__ gamma,
                                              const float* __restrict__ beta,
                                              float* __restrict__ out) {
  __shared__ float tile[COUT][33];
  int b = blockIdx.x >> 7;
  int n0 = (blockIdx.x & 127) << 5;
  int t = threadIdx.x;
  const float inv = 1.0f / (float)BNK;
  float mean = gsum[t] * inv;
  float var  = gsq[t] * inv - mean * mean;
  float sc = gamma[t] * rsqrtf(var + 1e-5f);
  float sh = beta[t] - mean * sc;
  const unsigned short* src = (sc >= 0.f) ? nmaxh : nminh;
#pragma unroll
  for (int rr = 0; rr < 32; ++rr) {
    size_t g = (size_t)(b * NN + n0 + rr) * COUT + t;
    tile[t][rr] = bs2f(src[g]) * sc + sh;
  }
  __syncthreads();
#pragma unroll
  for (int i = 0; i < 32; ++i) {
    int o = i * 8 + (t >> 5);
    int nl = t & 31;
    out[((size_t)(b * COUT + o) * NN) + n0 + nl] = tile[o][nl];
  }
}

extern "C" void kernel_launch(void* const* d_in, const int* in_sizes, int n_in,
                              void* d_out, int out_size, void* d_ws, size_t ws_size,
                              hipStream_t stream) {
  const float* x     = (const float*)d_in[0];
  const float* w     = (const float*)d_in[1];
  const float* bias  = (const float*)d_in[2];
  const float* gamma = (const float*)d_in[3];
  const float* beta  = (const float*)d_in[4];
  const int*   eidx  = (const int*)d_in[5];

  // ws layout (33.6 MB; featbf/w12 lifetimes end at k1, overlapped by nmaxh):
  char* ws = (char*)d_ws;
  unsigned short* featbf = (unsigned short*)(ws);              // @0        4,194,304 B (dead after k1)
  unsigned short* w12    = (unsigned short*)(ws + 4194304);    // @4194304    131,072 B (dead after k1)
  unsigned short* nmaxh  = (unsigned short*)(ws);              // @0        8,388,608 B (written in k2)
  unsigned short* Ybuf   = (unsigned short*)(ws + 8388608);    // @8388608 16,777,216 B
  unsigned short* nminh  = (unsigned short*)(ws + 25165824);   // @25165824 8,388,608 B
  float* gsum = (float*)(ws + 33554432);                       //     1,024 B
  float* gsq  = (float*)(ws + 33555456);                       //     1,024 B
  float* out = (float*)d_out;

  k0_prep<<<256, 256, 0, stream>>>(x, featbf, w, w12, gsum, gsq);
  k1_gemm<<<1024, 256, 0, stream>>>(featbf, w12, Ybuf);
  k2_edge<<<1024, 256, 0, stream>>>(Ybuf, bias, eidx, nmaxh, nminh, gsum, gsq);
  k3_out<<<512, 256, 0, stream>>>(nmaxh, nminh, gsum, gsq, gamma, beta, out);
}